// Round 4
// baseline (649.104 us; speedup 1.0000x reference)
//
#include <hip/hip_runtime.h>
#include <hip/hip_bf16.h>
#include <cstdint>
#include <cstddef>

// Problem constants
#define B_N 8192
#define D_K 1024
#define H_N 400
#define HP  416          // H padded to multiple of 32
#define K2_N 512
#define E_N 16
#define L_N 256
#define TM 64
#define PAD_ROWS (B_N + E_N * TM)   // 9216
#define NTILES (PAD_ROWS / TM)      // 144
#define GRID 576                    // must be <= 256 CUs * 3 blocks/CU

typedef short bf16x8 __attribute__((ext_vector_type(8)));
typedef float f32x4 __attribute__((ext_vector_type(4)));

// async global->LDS, 16B per lane; LDS dest = wave-uniform base + lane*16.
// Global address may be fully per-lane (gather OK).
#define GLDS(gp, lp) __builtin_amdgcn_global_load_lds( \
    (const __attribute__((address_space(1))) unsigned int*)(gp), \
    (__attribute__((address_space(3))) unsigned int*)(lp), 16, 0, 0)

static __device__ __forceinline__ unsigned short f2bf(float f) {
  union { float f; unsigned int u; } c; c.f = f;
  unsigned int u = c.u + 0x7fffu + ((c.u >> 16) & 1u);  // RNE
  return (unsigned short)(u >> 16);
}
static __device__ __forceinline__ unsigned int pkbf(float a, float b) {
  union { __hip_bfloat162 v; unsigned int u; } c;
  c.v = __float22bfloat162_rn(make_float2(a, b));
  return c.u;
}

// Software grid barrier: all GRID blocks are co-resident (capacity-guaranteed
// by __launch_bounds__(256,3) + 49.7KB LDS -> 3 blocks/CU -> 768 slots >= 576).
// Device-scope release fence + atomic arrive; acquire fence by every thread
// after release so cross-XCD L2 writes are visible (G16 pattern).
static __device__ __forceinline__ void gbar(int* cnt) {
  __syncthreads();
  if (threadIdx.x == 0) {
    __threadfence();   // release: publish this block's global writes
    __hip_atomic_fetch_add(cnt, 1, __ATOMIC_RELEASE, __HIP_MEMORY_SCOPE_AGENT);
    while (__hip_atomic_load(cnt, __ATOMIC_ACQUIRE, __HIP_MEMORY_SCOPE_AGENT) < GRID)
      __builtin_amdgcn_s_sleep(2);
  }
  __syncthreads();
  __threadfence();     // acquire for all threads of the block
}

// ---------------- fused pipeline: prep -> gbar -> gemm1 -> gbar -> gemm2 ----
// Phase bodies are identical to the previously verified standalone kernels;
// prep is grid-strided over its 3232 units.
__global__ __launch_bounds__(256, 3) void fused_kernel(
    const float* __restrict__ W1, const float* __restrict__ W2,
    const float* __restrict__ x, const int* __restrict__ idx,
    const float* __restrict__ b1, const float* __restrict__ b2,
    unsigned short* __restrict__ Wt1, unsigned short* __restrict__ Wt2,
    unsigned short* __restrict__ xc, unsigned short* __restrict__ h1buf,
    int* __restrict__ off_al, int* __restrict__ cnt_al,
    int* __restrict__ order, float* __restrict__ out, int* __restrict__ bar) {
  __shared__ union {
    unsigned short Ls[64][72];                                  // prep transpose
    struct { unsigned short As[2 * 2 * 2048];                   // gemm staging
             unsigned short Bs[2 * 2 * 4096]; } g;              // 48 KB total
  } U;
  __shared__ int offs[E_N + 1];
  __shared__ int rowidx[TM];
  __shared__ int totL[E_N], preL[E_N], offsL[E_N], curL[E_N];

  const int t = threadIdx.x;
  const int blk = blockIdx.x;

  // ================= phase 1: prep (grid-stride over 3232 units) ============
  for (int unit = blk; unit < 3232; unit += GRID) {
    if (unit < 2688) {
      const float* S; unsigned short* Dt; int K, N, Kd, Nd, k0, n0;
      if (unit < 1792) {                   // W1: 16 k-blocks x 7 n-blocks x 16 e
        int e = unit / 112, r = unit % 112;
        k0 = (r % 16) * 64; n0 = (r / 16) * 64;
        S = W1 + (size_t)e * D_K * H_N; Dt = Wt1 + (size_t)e * HP * D_K;
        K = D_K; N = H_N; Kd = D_K; Nd = HP;
      } else {                             // W2: 7 k-blocks x 8 n-blocks x 16 e
        int t2 = unit - 1792; int e = t2 / 56, r = t2 % 56;
        k0 = (r % 7) * 64; n0 = (r / 7) * 64;
        S = W2 + (size_t)e * H_N * K2_N; Dt = Wt2 + (size_t)e * K2_N * HP;
        K = H_N; N = K2_N; Kd = HP; Nd = K2_N;
      }
      const int kk = t >> 4;
      const int nn = (t & 15) * 4;
      float4 v[4];
#pragma unroll
      for (int p = 0; p < 4; ++p) {
        int k = k0 + p * 16 + kk;
        int n = n0 + nn;
        v[p] = make_float4(0.f, 0.f, 0.f, 0.f);
        if (k < K && n + 3 < N) v[p] = *(const float4*)(S + (size_t)k * N + n);
      }
#pragma unroll
      for (int p = 0; p < 4; ++p) {
        U.Ls[nn + 0][p * 16 + kk] = f2bf(v[p].x);
        U.Ls[nn + 1][p * 16 + kk] = f2bf(v[p].y);
        U.Ls[nn + 2][p * 16 + kk] = f2bf(v[p].z);
        U.Ls[nn + 3][p * 16 + kk] = f2bf(v[p].w);
      }
      __syncthreads();
      const int n2 = t >> 3;
      const int ch = t & 7;
#pragma unroll
      for (int p = 0; p < 2; ++p) {
        int n = n0 + p * 32 + n2;
        int k = k0 + ch * 8;
        if (n < Nd && k < Kd)
          *(uint4*)(Dt + (size_t)n * Kd + k) = *(const uint4*)&U.Ls[p * 32 + n2][ch * 8];
      }
    } else if (unit < 3200) {
      const int xb = unit - 2688;
      const float* S = x + (size_t)xb * 16 * D_K;
      unsigned short* Dp = xc + (size_t)xb * 16 * D_K;
#pragma unroll
      for (int i = 0; i < 16; ++i) {
        float4 v = *(const float4*)(S + i * D_K + t * 4);
        uint2 o; o.x = pkbf(v.x, v.y); o.y = pkbf(v.z, v.w);
        *(uint2*)(Dp + i * D_K + t * 4) = o;
      }
    } else {
      const int hb = unit - 3200;
      if (t < E_N) { totL[t] = 0; preL[t] = 0; }
      __syncthreads();
      const int lim = hb * 256;
      for (int i = t; i < B_N; i += 256) {
        const int e0 = idx[i];
        atomicAdd(&totL[e0], 1);
        if (i < lim) atomicAdd(&preL[e0], 1);
      }
      __syncthreads();
      if (t == 0) {
        int acc = 0;
        for (int e = 0; e < E_N; ++e) {
          offsL[e] = acc;
          if (hb == 0) off_al[e] = acc;
          acc += ((totL[e] + TM - 1) / TM) * TM;
        }
        if (hb == 0) off_al[E_N] = acc;
      }
      __syncthreads();
      if (t < E_N) {
        curL[t] = offsL[t] + preL[t];
        if (hb == 0) cnt_al[t] = totL[t];
      }
      __syncthreads();
      const int b = hb * 256 + t;
      const int e = idx[b];
      const int slot = atomicAdd(&curL[e], 1);
      order[slot] = b;
      if (hb == 0) *(uint2*)(xc + (size_t)B_N * D_K + t * 4) = make_uint2(0, 0);
    }
    __syncthreads();   // LDS reuse across grid-stride units
  }

  gbar(&bar[0]);

  // XCD-clustering decode (same bijection as before): each XCD owns 18
  // consecutive m-tiles x all 4 n-chunks.
  const int vid = (blk & 7) * 72 + (blk >> 3);
  const int mt = vid >> 2;
  const int nb = vid & 3;
  const int m0 = mt * TM;

  const int l = t & 63, w = t >> 6;
  const int r4 = l >> 2;
  const int sg = (r4 ^ (r4 >> 2)) & 3;
  const int g8 = ((l & 3) ^ sg) * 8;
  const int ln = l & 15, q = l >> 4;
  const int sr = (ln ^ (ln >> 2)) & 3;
  const int cq = (q ^ sr) * 8;
  const int t0 = nb * 8 + 2 * w;

  // ================= phase 2: gemm1 =========================================
  if (t <= E_N) offs[t] = off_al[t];
  __syncthreads();
  const bool bact = (m0 < offs[E_N]);
  int e = 0;
  if (bact) {
    while (m0 >= offs[e + 1]) ++e;
    if (t < TM) {
      const bool valid = (m0 + t) < (offs[e] + cnt_al[e]);
      rowidx[t] = valid ? order[m0 + t] : B_N;   // pad -> zero row
    }
    __syncthreads();
    const unsigned short* Wt1e = Wt1 + (size_t)e * HP * D_K;
    const bool act0 = (t0 < 25);
    const bool act1 = (t0 + 1 < 25);
    const unsigned short* gA = xc + (size_t)rowidx[16 * w + r4] * D_K + g8;
    const unsigned short* gB0 = Wt1e + (size_t)(t0 * 16 + r4) * D_K + g8;
    const unsigned short* gB1 = gB0 + (size_t)16 * D_K;

    f32x4 acc[4][2] = {};

#pragma unroll
    for (int ks = 0; ks < 2; ++ks) {
      GLDS(gA + ks * 32, &U.g.As[ks * 2048 + 16 * w * 32]);
      if (act0) GLDS(gB0 + ks * 32, &U.g.Bs[ks * 4096 + (2 * w + 0) * 512]);
      if (act1) GLDS(gB1 + ks * 32, &U.g.Bs[ks * 4096 + (2 * w + 1) * 512]);
    }

    for (int k0 = 0; k0 < D_K; k0 += 64) {    // 16 iterations
      const int cur = (k0 >> 6) & 1;
      const int nxt = cur ^ 1;
      __syncthreads();
      if (k0 + 64 < D_K) {
#pragma unroll
        for (int ks = 0; ks < 2; ++ks) {
          const int kg = k0 + 64 + ks * 32;
          GLDS(gA + kg, &U.g.As[nxt * 4096 + ks * 2048 + 16 * w * 32]);
          if (act0) GLDS(gB0 + kg, &U.g.Bs[nxt * 8192 + ks * 4096 + (2 * w + 0) * 512]);
          if (act1) GLDS(gB1 + kg, &U.g.Bs[nxt * 8192 + ks * 4096 + (2 * w + 1) * 512]);
        }
      }
      if (act0) {
#pragma unroll
        for (int ks = 0; ks < 2; ++ks) {
          const unsigned short* Ab = &U.g.As[cur * 4096 + ks * 2048];
          const unsigned short* Bb = &U.g.Bs[cur * 8192 + ks * 4096];
          bf16x8 af[4];
#pragma unroll
          for (int i = 0; i < 4; ++i)
            af[i] = *(const bf16x8*)&Ab[(16 * i + ln) * 32 + cq];
          bf16x8 b0f = *(const bf16x8*)&Bb[(2 * w + 0) * 512 + ln * 32 + cq];
#pragma unroll
          for (int i = 0; i < 4; ++i)
            acc[i][0] = __builtin_amdgcn_mfma_f32_16x16x32_bf16(b0f, af[i], acc[i][0], 0, 0, 0);
          if (act1) {
            bf16x8 b1f = *(const bf16x8*)&Bb[(2 * w + 1) * 512 + ln * 32 + cq];
#pragma unroll
            for (int i = 0; i < 4; ++i)
              acc[i][1] = __builtin_amdgcn_mfma_f32_16x16x32_bf16(b1f, af[i], acc[i][1], 0, 0, 0);
          }
        }
      }
    }

#pragma unroll
    for (int j = 0; j < 2; ++j) {
      if (j == 0 ? act0 : act1) {
        const int n4 = (t0 + j) * 16 + 4 * q;          // always < 400
        const float4 bv = *(const float4*)&b1[e * H_N + n4];
#pragma unroll
        for (int i = 0; i < 4; ++i) {
          const size_t m = (size_t)(m0 + 16 * i + ln);
          uint2 o;
          o.x = pkbf(fmaxf(acc[i][j][0] + bv.x, 0.f), fmaxf(acc[i][j][1] + bv.y, 0.f));
          o.y = pkbf(fmaxf(acc[i][j][2] + bv.z, 0.f), fmaxf(acc[i][j][3] + bv.w, 0.f));
          *(uint2*)&h1buf[m * HP + n4] = o;
        }
      }
    }
    // h1 pad cols [400,416) stay unwritten: Wt2 rows there are zero.
  }

  gbar(&bar[1]);

  // ================= phase 3: gemm2 =========================================
  if (bact) {
    if (t < TM) {
      const bool valid = (m0 + t) < (offs[e] + cnt_al[e]);
      rowidx[t] = valid ? order[m0 + t] : -1;
    }
    __syncthreads();
    const unsigned short* Wt2e = Wt2 + (size_t)e * K2_N * HP;
    const unsigned short* gA = h1buf + (size_t)(m0 + 16 * w + r4) * HP + g8;
    const unsigned short* gB0 = Wt2e + (size_t)(t0 * 16 + r4) * HP + g8;
    const unsigned short* gB1 = gB0 + (size_t)16 * HP;

    f32x4 acc[4][2] = {};

#pragma unroll
    for (int ks = 0; ks < 2; ++ks) {
      GLDS(gA + ks * 32, &U.g.As[ks * 2048 + 16 * w * 32]);
      GLDS(gB0 + ks * 32, &U.g.Bs[ks * 4096 + (2 * w + 0) * 512]);
      GLDS(gB1 + ks * 32, &U.g.Bs[ks * 4096 + (2 * w + 1) * 512]);
    }

    for (int k0 = 0; k0 < HP; k0 += 64) {     // 7 iterations (last = half)
      const int cur = (k0 >> 6) & 1;
      const int nxt = cur ^ 1;
      __syncthreads();
#pragma unroll
      for (int ks = 0; ks < 2; ++ks) {
        const int kg = k0 + 64 + ks * 32;
        if (kg < HP) {
          GLDS(gA + kg, &U.g.As[nxt * 4096 + ks * 2048 + 16 * w * 32]);
          GLDS(gB0 + kg, &U.g.Bs[nxt * 8192 + ks * 4096 + (2 * w + 0) * 512]);
          GLDS(gB1 + kg, &U.g.Bs[nxt * 8192 + ks * 4096 + (2 * w + 1) * 512]);
        }
      }
#pragma unroll
      for (int ks = 0; ks < 2; ++ks) {
        if (k0 + ks * 32 < HP) {
          const unsigned short* Ab = &U.g.As[cur * 4096 + ks * 2048];
          const unsigned short* Bb = &U.g.Bs[cur * 8192 + ks * 4096];
          bf16x8 af[4];
#pragma unroll
          for (int i = 0; i < 4; ++i)
            af[i] = *(const bf16x8*)&Ab[(16 * i + ln) * 32 + cq];
          bf16x8 b0f = *(const bf16x8*)&Bb[(2 * w + 0) * 512 + ln * 32 + cq];
#pragma unroll
          for (int i = 0; i < 4; ++i)
            acc[i][0] = __builtin_amdgcn_mfma_f32_16x16x32_bf16(b0f, af[i], acc[i][0], 0, 0, 0);
          bf16x8 b1f = *(const bf16x8*)&Bb[(2 * w + 1) * 512 + ln * 32 + cq];
#pragma unroll
          for (int i = 0; i < 4; ++i)
            acc[i][1] = __builtin_amdgcn_mfma_f32_16x16x32_bf16(b1f, af[i], acc[i][1], 0, 0, 0);
        }
      }
    }

#pragma unroll
    for (int j = 0; j < 2; ++j) {
      const int n4 = (t0 + j) * 16 + 4 * q;
      const float4 bv = *(const float4*)&b2[e * K2_N + n4];
#pragma unroll
      for (int i = 0; i < 4; ++i) {
        const int s = rowidx[16 * i + ln];
        if (s >= 0) {
          float4 v;
          v.x = acc[i][j][0] + bv.x;
          v.y = acc[i][j][1] + bv.y;
          v.z = acc[i][j][2] + bv.z;
          v.w = acc[i][j][3] + bv.w;
          if (n4 < L_N) *(float4*)&out[(size_t)s * L_N + n4] = v;
          else          *(float4*)&out[(size_t)(B_N + s) * L_N + (n4 - L_N)] = v;
        }
      }
    }
  }
}

extern "C" void kernel_launch(void* const* d_in, const int* in_sizes, int n_in,
                              void* d_out, int out_size, void* d_ws, size_t ws_size,
                              hipStream_t stream) {
  const float* x   = (const float*)d_in[0];
  const int*   idx = (const int*)d_in[1];
  const float* W1  = (const float*)d_in[2];
  const float* b1  = (const float*)d_in[3];
  const float* W2  = (const float*)d_in[4];
  const float* b2  = (const float*)d_in[5];
  float* out = (float*)d_out;

  // ws layout (bytes), total ~44.9 MB:
  // off_al@0 (68) | cnt_al@128 (64) | bar@192 (8) | order@2240 (36864)
  // xc@39104 ((8192+1)x1024x2) | h1@16,818,368 (9216x416x2)
  // Wt1@24,486,080 (16x416x1024x2) | Wt2@38,117,568 (16x512x416x2) -> 44,933,312
  char* ws = (char*)d_ws;
  int* off_al = (int*)(ws + 0);
  int* cnt_al = (int*)(ws + 128);
  int* bar    = (int*)(ws + 192);
  int* order  = (int*)(ws + 2240);
  unsigned short* xc  = (unsigned short*)(ws + 39104);
  unsigned short* h1  = (unsigned short*)(ws + 16818368);
  unsigned short* Wt1 = (unsigned short*)(ws + 24486080);
  unsigned short* Wt2 = (unsigned short*)(ws + 38117568);

  hipMemsetAsync(bar, 0, 8, stream);   // barrier counters (ws is re-poisoned)
  fused_kernel<<<GRID, 256, 0, stream>>>(W1, W2, x, idx, b1, b2, Wt1, Wt2, xc,
                                         h1, off_al, cnt_al, order, out, bar);
}

// Round 5
// 338.418 us; speedup vs baseline: 1.9181x; 1.9181x over previous
//
#include <hip/hip_runtime.h>
#include <hip/hip_bf16.h>
#include <cstdint>
#include <cstddef>

// Problem constants
#define B_N 8192
#define D_K 1024
#define H_N 400
#define HP  416          // H padded to multiple of 32
#define K2_N 512
#define E_N 16
#define L_N 256
#define TM 64
#define PAD_ROWS (B_N + E_N * TM)   // 9216
#define NTILES (PAD_ROWS / TM)      // 144
#define GRID 576                    // must be <= 256 CUs * 3 blocks/CU

typedef short bf16x8 __attribute__((ext_vector_type(8)));
typedef float f32x4 __attribute__((ext_vector_type(4)));

// async global->LDS, 16B per lane; LDS dest = wave-uniform base + lane*16.
// Global address may be fully per-lane (gather OK).
#define GLDS(gp, lp) __builtin_amdgcn_global_load_lds( \
    (const __attribute__((address_space(1))) unsigned int*)(gp), \
    (__attribute__((address_space(3))) unsigned int*)(lp), 16, 0, 0)

static __device__ __forceinline__ unsigned short f2bf(float f) {
  union { float f; unsigned int u; } c; c.f = f;
  unsigned int u = c.u + 0x7fffu + ((c.u >> 16) & 1u);  // RNE
  return (unsigned short)(u >> 16);
}
static __device__ __forceinline__ unsigned int pkbf(float a, float b) {
  union { __hip_bfloat162 v; unsigned int u; } c;
  c.v = __float22bfloat162_rn(make_float2(a, b));
  return c.u;
}

// Software grid barrier: all GRID blocks are co-resident (capacity-guaranteed
// by __launch_bounds__(256,3) + 49KB LDS -> 3 blocks/CU -> 768 slots >= 576;
// measured round-4 occupancy 27.2% == 9 waves/CU confirms full residency).
//
// CRITICAL (round-4 lesson, 570us @ 0.9% VALUBusy): the spin must use a
// RELAXED atomic load. An ACQUIRE load at agent scope emits a cache
// invalidation on EVERY poll, continuously nuking the XCD's L2 and turning
// every co-located block's load into a ~900cy HBM miss. Pattern here:
// release RMW (publishes this block's writes) -> relaxed spin (coherent
// read, no invalidation) -> ONE acquire fence per block after exit.
static __device__ __forceinline__ void gbar(int* cnt) {
  __syncthreads();
  if (threadIdx.x == 0) {
    __hip_atomic_fetch_add(cnt, 1, __ATOMIC_RELEASE, __HIP_MEMORY_SCOPE_AGENT);
    while (__hip_atomic_load(cnt, __ATOMIC_RELAXED, __HIP_MEMORY_SCOPE_AGENT) < GRID)
      __builtin_amdgcn_s_sleep(8);
  }
  __syncthreads();
  __threadfence();   // single acquire: invalidate stale L1/L2 once, then read peers' data
}

// ---------------- fused pipeline: prep -> gbar -> gemm1 -> gbar -> gemm2 ----
// Phase bodies are identical to the previously verified standalone kernels;
// prep is grid-strided over its 3232 units.
__global__ __launch_bounds__(256, 3) void fused_kernel(
    const float* __restrict__ W1, const float* __restrict__ W2,
    const float* __restrict__ x, const int* __restrict__ idx,
    const float* __restrict__ b1, const float* __restrict__ b2,
    unsigned short* __restrict__ Wt1, unsigned short* __restrict__ Wt2,
    unsigned short* __restrict__ xc, unsigned short* __restrict__ h1buf,
    int* __restrict__ off_al, int* __restrict__ cnt_al,
    int* __restrict__ order, float* __restrict__ out, int* __restrict__ bar) {
  __shared__ union {
    unsigned short Ls[64][72];                                  // prep transpose
    struct { unsigned short As[2 * 2 * 2048];                   // gemm staging
             unsigned short Bs[2 * 2 * 4096]; } g;              // 48 KB total
  } U;
  __shared__ int offs[E_N + 1];
  __shared__ int rowidx[TM];
  __shared__ int totL[E_N], preL[E_N], offsL[E_N], curL[E_N];

  const int t = threadIdx.x;
  const int blk = blockIdx.x;

  // ================= phase 1: prep (grid-stride over 3232 units) ============
  for (int unit = blk; unit < 3232; unit += GRID) {
    if (unit < 2688) {
      const float* S; unsigned short* Dt; int K, N, Kd, Nd, k0, n0;
      if (unit < 1792) {                   // W1: 16 k-blocks x 7 n-blocks x 16 e
        int e = unit / 112, r = unit % 112;
        k0 = (r % 16) * 64; n0 = (r / 16) * 64;
        S = W1 + (size_t)e * D_K * H_N; Dt = Wt1 + (size_t)e * HP * D_K;
        K = D_K; N = H_N; Kd = D_K; Nd = HP;
      } else {                             // W2: 7 k-blocks x 8 n-blocks x 16 e
        int t2 = unit - 1792; int e = t2 / 56, r = t2 % 56;
        k0 = (r % 7) * 64; n0 = (r / 7) * 64;
        S = W2 + (size_t)e * H_N * K2_N; Dt = Wt2 + (size_t)e * K2_N * HP;
        K = H_N; N = K2_N; Kd = HP; Nd = K2_N;
      }
      const int kk = t >> 4;
      const int nn = (t & 15) * 4;
      float4 v[4];
#pragma unroll
      for (int p = 0; p < 4; ++p) {
        int k = k0 + p * 16 + kk;
        int n = n0 + nn;
        v[p] = make_float4(0.f, 0.f, 0.f, 0.f);
        if (k < K && n + 3 < N) v[p] = *(const float4*)(S + (size_t)k * N + n);
      }
#pragma unroll
      for (int p = 0; p < 4; ++p) {
        U.Ls[nn + 0][p * 16 + kk] = f2bf(v[p].x);
        U.Ls[nn + 1][p * 16 + kk] = f2bf(v[p].y);
        U.Ls[nn + 2][p * 16 + kk] = f2bf(v[p].z);
        U.Ls[nn + 3][p * 16 + kk] = f2bf(v[p].w);
      }
      __syncthreads();
      const int n2 = t >> 3;
      const int ch = t & 7;
#pragma unroll
      for (int p = 0; p < 2; ++p) {
        int n = n0 + p * 32 + n2;
        int k = k0 + ch * 8;
        if (n < Nd && k < Kd)
          *(uint4*)(Dt + (size_t)n * Kd + k) = *(const uint4*)&U.Ls[p * 32 + n2][ch * 8];
      }
    } else if (unit < 3200) {
      const int xb = unit - 2688;
      const float* S = x + (size_t)xb * 16 * D_K;
      unsigned short* Dp = xc + (size_t)xb * 16 * D_K;
#pragma unroll
      for (int i = 0; i < 16; ++i) {
        float4 v = *(const float4*)(S + i * D_K + t * 4);
        uint2 o; o.x = pkbf(v.x, v.y); o.y = pkbf(v.z, v.w);
        *(uint2*)(Dp + i * D_K + t * 4) = o;
      }
    } else {
      const int hb = unit - 3200;
      if (t < E_N) { totL[t] = 0; preL[t] = 0; }
      __syncthreads();
      const int lim = hb * 256;
      for (int i = t; i < B_N; i += 256) {
        const int e0 = idx[i];
        atomicAdd(&totL[e0], 1);
        if (i < lim) atomicAdd(&preL[e0], 1);
      }
      __syncthreads();
      if (t == 0) {
        int acc = 0;
        for (int e = 0; e < E_N; ++e) {
          offsL[e] = acc;
          if (hb == 0) off_al[e] = acc;
          acc += ((totL[e] + TM - 1) / TM) * TM;
        }
        if (hb == 0) off_al[E_N] = acc;
      }
      __syncthreads();
      if (t < E_N) {
        curL[t] = offsL[t] + preL[t];
        if (hb == 0) cnt_al[t] = totL[t];
      }
      __syncthreads();
      const int b = hb * 256 + t;
      const int e = idx[b];
      const int slot = atomicAdd(&curL[e], 1);
      order[slot] = b;
      if (hb == 0) *(uint2*)(xc + (size_t)B_N * D_K + t * 4) = make_uint2(0, 0);
    }
    __syncthreads();   // LDS reuse across grid-stride units
  }

  gbar(&bar[0]);

  // XCD-clustering decode (same bijection as before): each XCD owns 18
  // consecutive m-tiles x all 4 n-chunks.
  const int vid = (blk & 7) * 72 + (blk >> 3);
  const int mt = vid >> 2;
  const int nb = vid & 3;
  const int m0 = mt * TM;

  const int l = t & 63, w = t >> 6;
  const int r4 = l >> 2;
  const int sg = (r4 ^ (r4 >> 2)) & 3;
  const int g8 = ((l & 3) ^ sg) * 8;
  const int ln = l & 15, q = l >> 4;
  const int sr = (ln ^ (ln >> 2)) & 3;
  const int cq = (q ^ sr) * 8;
  const int t0 = nb * 8 + 2 * w;

  // ================= phase 2: gemm1 =========================================
  if (t <= E_N) offs[t] = off_al[t];
  __syncthreads();
  const bool bact = (m0 < offs[E_N]);
  int e = 0;
  if (bact) {
    while (m0 >= offs[e + 1]) ++e;
    if (t < TM) {
      const bool valid = (m0 + t) < (offs[e] + cnt_al[e]);
      rowidx[t] = valid ? order[m0 + t] : B_N;   // pad -> zero row
    }
    __syncthreads();
    const unsigned short* Wt1e = Wt1 + (size_t)e * HP * D_K;
    const bool act0 = (t0 < 25);
    const bool act1 = (t0 + 1 < 25);
    const unsigned short* gA = xc + (size_t)rowidx[16 * w + r4] * D_K + g8;
    const unsigned short* gB0 = Wt1e + (size_t)(t0 * 16 + r4) * D_K + g8;
    const unsigned short* gB1 = gB0 + (size_t)16 * D_K;

    f32x4 acc[4][2] = {};

#pragma unroll
    for (int ks = 0; ks < 2; ++ks) {
      GLDS(gA + ks * 32, &U.g.As[ks * 2048 + 16 * w * 32]);
      if (act0) GLDS(gB0 + ks * 32, &U.g.Bs[ks * 4096 + (2 * w + 0) * 512]);
      if (act1) GLDS(gB1 + ks * 32, &U.g.Bs[ks * 4096 + (2 * w + 1) * 512]);
    }

    for (int k0 = 0; k0 < D_K; k0 += 64) {    // 16 iterations
      const int cur = (k0 >> 6) & 1;
      const int nxt = cur ^ 1;
      __syncthreads();
      if (k0 + 64 < D_K) {
#pragma unroll
        for (int ks = 0; ks < 2; ++ks) {
          const int kg = k0 + 64 + ks * 32;
          GLDS(gA + kg, &U.g.As[nxt * 4096 + ks * 2048 + 16 * w * 32]);
          if (act0) GLDS(gB0 + kg, &U.g.Bs[nxt * 8192 + ks * 4096 + (2 * w + 0) * 512]);
          if (act1) GLDS(gB1 + kg, &U.g.Bs[nxt * 8192 + ks * 4096 + (2 * w + 1) * 512]);
        }
      }
      if (act0) {
#pragma unroll
        for (int ks = 0; ks < 2; ++ks) {
          const unsigned short* Ab = &U.g.As[cur * 4096 + ks * 2048];
          const unsigned short* Bb = &U.g.Bs[cur * 8192 + ks * 4096];
          bf16x8 af[4];
#pragma unroll
          for (int i = 0; i < 4; ++i)
            af[i] = *(const bf16x8*)&Ab[(16 * i + ln) * 32 + cq];
          bf16x8 b0f = *(const bf16x8*)&Bb[(2 * w + 0) * 512 + ln * 32 + cq];
#pragma unroll
          for (int i = 0; i < 4; ++i)
            acc[i][0] = __builtin_amdgcn_mfma_f32_16x16x32_bf16(b0f, af[i], acc[i][0], 0, 0, 0);
          if (act1) {
            bf16x8 b1f = *(const bf16x8*)&Bb[(2 * w + 1) * 512 + ln * 32 + cq];
#pragma unroll
            for (int i = 0; i < 4; ++i)
              acc[i][1] = __builtin_amdgcn_mfma_f32_16x16x32_bf16(b1f, af[i], acc[i][1], 0, 0, 0);
          }
        }
      }
    }

#pragma unroll
    for (int j = 0; j < 2; ++j) {
      if (j == 0 ? act0 : act1) {
        const int n4 = (t0 + j) * 16 + 4 * q;          // always < 400
        const float4 bv = *(const float4*)&b1[e * H_N + n4];
#pragma unroll
        for (int i = 0; i < 4; ++i) {
          const size_t m = (size_t)(m0 + 16 * i + ln);
          uint2 o;
          o.x = pkbf(fmaxf(acc[i][j][0] + bv.x, 0.f), fmaxf(acc[i][j][1] + bv.y, 0.f));
          o.y = pkbf(fmaxf(acc[i][j][2] + bv.z, 0.f), fmaxf(acc[i][j][3] + bv.w, 0.f));
          *(uint2*)&h1buf[m * HP + n4] = o;
        }
      }
    }
    // h1 pad cols [400,416) stay unwritten: Wt2 rows there are zero.
  }

  gbar(&bar[1]);

  // ================= phase 3: gemm2 =========================================
  if (bact) {
    if (t < TM) {
      const bool valid = (m0 + t) < (offs[e] + cnt_al[e]);
      rowidx[t] = valid ? order[m0 + t] : -1;
    }
    __syncthreads();
    const unsigned short* Wt2e = Wt2 + (size_t)e * K2_N * HP;
    const unsigned short* gA = h1buf + (size_t)(m0 + 16 * w + r4) * HP + g8;
    const unsigned short* gB0 = Wt2e + (size_t)(t0 * 16 + r4) * HP + g8;
    const unsigned short* gB1 = gB0 + (size_t)16 * HP;

    f32x4 acc[4][2] = {};

#pragma unroll
    for (int ks = 0; ks < 2; ++ks) {
      GLDS(gA + ks * 32, &U.g.As[ks * 2048 + 16 * w * 32]);
      GLDS(gB0 + ks * 32, &U.g.Bs[ks * 4096 + (2 * w + 0) * 512]);
      GLDS(gB1 + ks * 32, &U.g.Bs[ks * 4096 + (2 * w + 1) * 512]);
    }

    for (int k0 = 0; k0 < HP; k0 += 64) {     // 7 iterations (last = half)
      const int cur = (k0 >> 6) & 1;
      const int nxt = cur ^ 1;
      __syncthreads();
#pragma unroll
      for (int ks = 0; ks < 2; ++ks) {
        const int kg = k0 + 64 + ks * 32;
        if (kg < HP) {
          GLDS(gA + kg, &U.g.As[nxt * 4096 + ks * 2048 + 16 * w * 32]);
          GLDS(gB0 + kg, &U.g.Bs[nxt * 8192 + ks * 4096 + (2 * w + 0) * 512]);
          GLDS(gB1 + kg, &U.g.Bs[nxt * 8192 + ks * 4096 + (2 * w + 1) * 512]);
        }
      }
#pragma unroll
      for (int ks = 0; ks < 2; ++ks) {
        if (k0 + ks * 32 < HP) {
          const unsigned short* Ab = &U.g.As[cur * 4096 + ks * 2048];
          const unsigned short* Bb = &U.g.Bs[cur * 8192 + ks * 4096];
          bf16x8 af[4];
#pragma unroll
          for (int i = 0; i < 4; ++i)
            af[i] = *(const bf16x8*)&Ab[(16 * i + ln) * 32 + cq];
          bf16x8 b0f = *(const bf16x8*)&Bb[(2 * w + 0) * 512 + ln * 32 + cq];
#pragma unroll
          for (int i = 0; i < 4; ++i)
            acc[i][0] = __builtin_amdgcn_mfma_f32_16x16x32_bf16(b0f, af[i], acc[i][0], 0, 0, 0);
          bf16x8 b1f = *(const bf16x8*)&Bb[(2 * w + 1) * 512 + ln * 32 + cq];
#pragma unroll
          for (int i = 0; i < 4; ++i)
            acc[i][1] = __builtin_amdgcn_mfma_f32_16x16x32_bf16(b1f, af[i], acc[i][1], 0, 0, 0);
        }
      }
    }

#pragma unroll
    for (int j = 0; j < 2; ++j) {
      const int n4 = (t0 + j) * 16 + 4 * q;
      const float4 bv = *(const float4*)&b2[e * K2_N + n4];
#pragma unroll
      for (int i = 0; i < 4; ++i) {
        const int s = rowidx[16 * i + ln];
        if (s >= 0) {
          float4 v;
          v.x = acc[i][j][0] + bv.x;
          v.y = acc[i][j][1] + bv.y;
          v.z = acc[i][j][2] + bv.z;
          v.w = acc[i][j][3] + bv.w;
          if (n4 < L_N) *(float4*)&out[(size_t)s * L_N + n4] = v;
          else          *(float4*)&out[(size_t)(B_N + s) * L_N + (n4 - L_N)] = v;
        }
      }
    }
  }
}

extern "C" void kernel_launch(void* const* d_in, const int* in_sizes, int n_in,
                              void* d_out, int out_size, void* d_ws, size_t ws_size,
                              hipStream_t stream) {
  const float* x   = (const float*)d_in[0];
  const int*   idx = (const int*)d_in[1];
  const float* W1  = (const float*)d_in[2];
  const float* b1  = (const float*)d_in[3];
  const float* W2  = (const float*)d_in[4];
  const float* b2  = (const float*)d_in[5];
  float* out = (float*)d_out;

  // ws layout (bytes), total ~44.9 MB:
  // off_al@0 (68) | cnt_al@128 (64) | bar@192 (8) | order@2240 (36864)
  // xc@39104 ((8192+1)x1024x2) | h1@16,818,368 (9216x416x2)
  // Wt1@24,486,080 (16x416x1024x2) | Wt2@38,117,568 (16x512x416x2) -> 44,933,312
  char* ws = (char*)d_ws;
  int* off_al = (int*)(ws + 0);
  int* cnt_al = (int*)(ws + 128);
  int* bar    = (int*)(ws + 192);
  int* order  = (int*)(ws + 2240);
  unsigned short* xc  = (unsigned short*)(ws + 39104);
  unsigned short* h1  = (unsigned short*)(ws + 16818368);
  unsigned short* Wt1 = (unsigned short*)(ws + 24486080);
  unsigned short* Wt2 = (unsigned short*)(ws + 38117568);

  hipMemsetAsync(bar, 0, 8, stream);   // barrier counters (ws is re-poisoned)
  fused_kernel<<<GRID, 256, 0, stream>>>(W1, W2, x, idx, b1, b2, Wt1, Wt2, xc,
                                         h1, off_al, cnt_al, order, out, bar);
}

// Round 6
// 182.969 us; speedup vs baseline: 3.5476x; 1.8496x over previous
//
#include <hip/hip_runtime.h>
#include <hip/hip_bf16.h>
#include <cstdint>
#include <cstddef>

// Problem constants
#define B_N 8192
#define D_K 1024
#define H_N 400
#define HP  416          // H padded to multiple of 32
#define HPAD 424         // h1 LDS row stride in shorts (bank-skew: 848B -> 8 bank offsets)
#define K2_N 512
#define E_N 16
#define L_N 256
#define TMR 32                        // rows per block (row-strip)
#define PAD_ROWS (B_N + E_N * TMR)    // 8704
#define NT2 (PAD_ROWS / TMR)          // 272 = 8 XCDs * 34

typedef short bf16x8 __attribute__((ext_vector_type(8)));
typedef float f32x4 __attribute__((ext_vector_type(4)));

// async global->LDS, 16B per lane; LDS dest = wave-uniform base + lane*16.
// Global address may be fully per-lane (gather OK).
#define GLDS(gp, lp) __builtin_amdgcn_global_load_lds( \
    (const __attribute__((address_space(1))) unsigned int*)(gp), \
    (__attribute__((address_space(3))) unsigned int*)(lp), 16, 0, 0)

static __device__ __forceinline__ unsigned short f2bf(float f) {
  union { float f; unsigned int u; } c; c.f = f;
  unsigned int u = c.u + 0x7fffu + ((c.u >> 16) & 1u);  // RNE
  return (unsigned short)(u >> 16);
}
static __device__ __forceinline__ unsigned int pkbf(float a, float b) {
  union { __hip_bfloat162 v; unsigned int u; } c;
  c.v = __float22bfloat162_rn(make_float2(a, b));
  return c.u;
}

// ---------------- prep (one launch, fully parallel blocks): ----------------
// [0,1792):    W1 transpose [1024][400] f32 -> [416][1024] bf16 (zero-pad)
// [1792,2688): W2 transpose [400][512] f32 -> [512][416] bf16 (zero-pad)
// [2688,3200): x convert f32 -> bf16 (16 rows/block)
// [3200,3232): scatter (hist self-computed per block from idx; LDS atomics).
//              Alignment now TMR=32. hb==0 publishes off_al/cnt_al + zeroes
//              xc pad row.
__global__ __launch_bounds__(256) void prep_kernel(const float* __restrict__ W1,
                                                   const float* __restrict__ W2,
                                                   const float* __restrict__ x,
                                                   const int* __restrict__ idx,
                                                   unsigned short* __restrict__ Wt1,
                                                   unsigned short* __restrict__ Wt2,
                                                   unsigned short* __restrict__ xc,
                                                   int* __restrict__ off_al,
                                                   int* __restrict__ cnt_al,
                                                   int* __restrict__ order) {
  const int bid = blockIdx.x;
  const int t = threadIdx.x;
  if (bid < 2688) {
    __shared__ unsigned short Ls[64][72];
    const float* S; unsigned short* Dt; int K, N, Kd, Nd, k0, n0;
    if (bid < 1792) {                    // W1: 16 k-blocks x 7 n-blocks x 16 e
      int e = bid / 112, r = bid % 112;
      k0 = (r % 16) * 64; n0 = (r / 16) * 64;
      S = W1 + (size_t)e * D_K * H_N; Dt = Wt1 + (size_t)e * HP * D_K;
      K = D_K; N = H_N; Kd = D_K; Nd = HP;
    } else {                             // W2: 7 k-blocks x 8 n-blocks x 16 e
      int t2 = bid - 1792; int e = t2 / 56, r = t2 % 56;
      k0 = (r % 7) * 64; n0 = (r / 7) * 64;
      S = W2 + (size_t)e * H_N * K2_N; Dt = Wt2 + (size_t)e * K2_N * HP;
      K = H_N; N = K2_N; Kd = HP; Nd = K2_N;
    }
    const int kk = t >> 4;
    const int nn = (t & 15) * 4;
    float4 v[4];
#pragma unroll
    for (int p = 0; p < 4; ++p) {
      int k = k0 + p * 16 + kk;
      int n = n0 + nn;
      v[p] = make_float4(0.f, 0.f, 0.f, 0.f);
      if (k < K && n + 3 < N) v[p] = *(const float4*)(S + (size_t)k * N + n);
    }
#pragma unroll
    for (int p = 0; p < 4; ++p) {
      Ls[nn + 0][p * 16 + kk] = f2bf(v[p].x);
      Ls[nn + 1][p * 16 + kk] = f2bf(v[p].y);
      Ls[nn + 2][p * 16 + kk] = f2bf(v[p].z);
      Ls[nn + 3][p * 16 + kk] = f2bf(v[p].w);
    }
    __syncthreads();
    const int n2 = t >> 3;
    const int ch = t & 7;
#pragma unroll
    for (int p = 0; p < 2; ++p) {
      int n = n0 + p * 32 + n2;
      int k = k0 + ch * 8;
      if (n < Nd && k < Kd)
        *(uint4*)(Dt + (size_t)n * Kd + k) = *(const uint4*)&Ls[p * 32 + n2][ch * 8];
    }
  } else if (bid < 3200) {
    const int xb = bid - 2688;
    const float* S = x + (size_t)xb * 16 * D_K;
    unsigned short* Dp = xc + (size_t)xb * 16 * D_K;
#pragma unroll
    for (int i = 0; i < 16; ++i) {
      float4 v = *(const float4*)(S + i * D_K + t * 4);
      uint2 o; o.x = pkbf(v.x, v.y); o.y = pkbf(v.z, v.w);
      *(uint2*)(Dp + i * D_K + t * 4) = o;
    }
  } else {
    const int hb = bid - 3200;
    __shared__ int totL[E_N], preL[E_N], offsL[E_N], curL[E_N];
    if (t < E_N) { totL[t] = 0; preL[t] = 0; }
    __syncthreads();
    const int lim = hb * 256;
    for (int i = t; i < B_N; i += 256) {
      const int e0 = idx[i];
      atomicAdd(&totL[e0], 1);
      if (i < lim) atomicAdd(&preL[e0], 1);
    }
    __syncthreads();
    if (t == 0) {
      int acc = 0;
      for (int e = 0; e < E_N; ++e) {
        offsL[e] = acc;
        if (hb == 0) off_al[e] = acc;
        acc += ((totL[e] + TMR - 1) / TMR) * TMR;
      }
      if (hb == 0) off_al[E_N] = acc;
    }
    __syncthreads();
    if (t < E_N) {
      curL[t] = offsL[t] + preL[t];
      if (hb == 0) cnt_al[t] = totL[t];
    }
    __syncthreads();
    const int b = hb * 256 + t;
    const int e = idx[b];
    const int slot = atomicAdd(&curL[e], 1);
    order[slot] = b;
    if (hb == 0) *(uint2*)(xc + (size_t)B_N * D_K + t * 4) = make_uint2(0, 0);
  }
}

// ---------------- mlp: per-block row-strip, gemm1 -> LDS h1 -> gemm2 --------
// One block = 32 gathered rows x ALL output columns. gemm2's dependency on
// gemm1 becomes block-local (h1 lives in LDS) -> no grid barrier, no h1 HBM
// round-trip, no gemm2 A-staging. B tiles processed in passes of <=13 (LDS
// slots); verified 32-wide swizzled staging + swapped-operand MFMA reused.
// h1 LDS row stride 424 shorts (848B): consecutive rows land 20 banks apart
// -> 16-lane ds_read_b128 spreads over 8 bank groups (2-way, free).
// A-frag read from h1s uses PLAIN chunk q*8: the staging source-XOR and the
// LDS read-XOR of the staged path cancel (sg(r4==ln)==sr(ln)), so the true
// fragment is lane(16q+ln) = A[row ln][k0+8q..+7].
__global__ __launch_bounds__(256) void mlp_kernel(
    const unsigned short* __restrict__ xc,
    const unsigned short* __restrict__ Wt1,
    const unsigned short* __restrict__ Wt2,
    const float* __restrict__ b1, const float* __restrict__ b2,
    const int* __restrict__ off_al, const int* __restrict__ cnt_al,
    const int* __restrict__ order, float* __restrict__ out) {
  __shared__ unsigned short h1s[TMR * HPAD];     // 27,136 B
  __shared__ unsigned short Bs[2 * 13 * 512];    // 26,624 B
  __shared__ unsigned short As[2 * 2 * 512];     //  4,096 B   (total ~58 KB)
  __shared__ int offs[E_N + 1];
  __shared__ int rowidx[TMR];
  const int t = threadIdx.x;
  // XCD clustering: 272 = 8*34 exact -> bijective; same-expert strips
  // (consecutive vid) stay on one XCD's L2 for weight-panel reuse.
  const int vid = (blockIdx.x & 7) * 34 + (blockIdx.x >> 3);
  const int m0 = vid * TMR;
  if (t <= E_N) offs[t] = off_al[t];
  __syncthreads();
  if (m0 >= offs[E_N]) return;
  int e = 0;
  while (m0 >= offs[e + 1]) ++e;
  if (t < TMR) {
    const bool valid = (m0 + t) < (offs[e] + cnt_al[e]);
    rowidx[t] = valid ? order[m0 + t] : -1;      // pad -> -1
  }
  // zero h1 pad cols [400,424): LDS is uninitialized (could be NaN bits)
  for (int z = t; z < TMR * 12; z += 256) {
    const int row = z / 12, c2 = z % 12;
    *(unsigned int*)&h1s[row * HPAD + 400 + c2 * 2] = 0u;
  }
  __syncthreads();

  const int l = t & 63, w = t >> 6;
  const int r4 = l >> 2;
  const int sgx = (r4 ^ (r4 >> 2)) & 3;
  const int g8 = ((l & 3) ^ sgx) * 8;
  const int ln = l & 15, q = l >> 4;
  const int srx = (ln ^ (ln >> 2)) & 3;
  const int cq = (q ^ srx) * 8;

  const int ar = (w < 2) ? rowidx[16 * w + r4] : -1;
  const unsigned short* gA = xc + (size_t)(ar < 0 ? B_N : ar) * D_K + g8;
  const unsigned short* Wt1e = Wt1 + (size_t)e * HP * D_K;
  const unsigned short* Wt2e = Wt2 + (size_t)e * K2_N * HP;

  // ============ gemm1: h1s = relu(gather(xc) @ Wt1^T + b1), 25 tiles ========
#pragma unroll 1
  for (int pass = 0; pass < 2; ++pass) {
    const int tstart = pass ? 13 : 0;
    const int tcnt = pass ? 12 : 13;
    const int nj = (tcnt - w + 3) >> 2;          // tiles for this wave (<=4)
    const unsigned short* gB[4];
#pragma unroll
    for (int j = 0; j < 4; ++j)
      gB[j] = Wt1e + (size_t)((tstart + w + 4 * j) * 16 + r4) * D_K + g8;
    f32x4 acc[4][2] = {};
    if (w < 2) GLDS(gA, &As[w * 512]);
#pragma unroll
    for (int j = 0; j < 4; ++j)
      if (j < nj) GLDS(gB[j], &Bs[(w + 4 * j) * 512]);
    for (int k0 = 0; k0 < D_K; k0 += 32) {       // 32 iterations
      const int cur = (k0 >> 5) & 1, nxt = cur ^ 1;
      __syncthreads();                            // publishes buf[cur]
      if (k0 + 32 < D_K) {
        if (w < 2) GLDS(gA + k0 + 32, &As[(nxt * 2 + w) * 512]);
#pragma unroll
        for (int j = 0; j < 4; ++j)
          if (j < nj) GLDS(gB[j] + k0 + 32, &Bs[(nxt * 13 + w + 4 * j) * 512]);
      }
      const bf16x8 af0 = *(const bf16x8*)&As[(cur * 2 + 0) * 512 + ln * 32 + cq];
      const bf16x8 af1 = *(const bf16x8*)&As[(cur * 2 + 1) * 512 + ln * 32 + cq];
#pragma unroll
      for (int j = 0; j < 4; ++j)
        if (j < nj) {
          const bf16x8 bf = *(const bf16x8*)&Bs[(cur * 13 + w + 4 * j) * 512 + ln * 32 + cq];
          acc[j][0] = __builtin_amdgcn_mfma_f32_16x16x32_bf16(bf, af0, acc[j][0], 0, 0, 0);
          acc[j][1] = __builtin_amdgcn_mfma_f32_16x16x32_bf16(bf, af1, acc[j][1], 0, 0, 0);
        }
    }
    __syncthreads();   // all Bs/As reads done before next pass re-stages buf0
    // epilogue: swapped layout -> lane holds m=16i+ln, n=tile*16+4q+reg
#pragma unroll
    for (int j = 0; j < 4; ++j)
      if (j < nj) {
        const int n4 = (tstart + w + 4 * j) * 16 + 4 * q;   // <= 396
        const float4 bv = *(const float4*)&b1[e * H_N + n4];
#pragma unroll
        for (int i = 0; i < 2; ++i) {
          const int m = 16 * i + ln;
          uint2 o;
          o.x = pkbf(fmaxf(acc[j][i][0] + bv.x, 0.f), fmaxf(acc[j][i][1] + bv.y, 0.f));
          o.y = pkbf(fmaxf(acc[j][i][2] + bv.z, 0.f), fmaxf(acc[j][i][3] + bv.w, 0.f));
          *(uint2*)&h1s[m * HPAD + n4] = o;
        }
      }
  }
  __syncthreads();   // h1s complete for all waves

  // ============ gemm2: out = h1s @ Wt2^T + b2, 32 tiles in 3 passes =========
#pragma unroll 1
  for (int pass = 0; pass < 3; ++pass) {
    const int tstart = pass * 13;
    const int tcnt = (pass == 2) ? 6 : 13;
    const int nj = (tcnt > w) ? ((tcnt - w + 3) >> 2) : 0;
    const unsigned short* gB[4];
#pragma unroll
    for (int j = 0; j < 4; ++j)
      gB[j] = Wt2e + (size_t)((tstart + w + 4 * j) * 16 + r4) * HP + g8;
    f32x4 acc[4][2] = {};
#pragma unroll
    for (int j = 0; j < 4; ++j)
      if (j < nj) GLDS(gB[j], &Bs[(w + 4 * j) * 512]);
    for (int k0 = 0; k0 < HP; k0 += 32) {        // 13 iterations
      const int cur = (k0 >> 5) & 1, nxt = cur ^ 1;
      __syncthreads();
      if (k0 + 32 < HP) {
#pragma unroll
        for (int j = 0; j < 4; ++j)
          if (j < nj) GLDS(gB[j] + k0 + 32, &Bs[(nxt * 13 + w + 4 * j) * 512]);
      }
      // A from LDS-resident h1 (plain fragment: chunk q*8, no XOR)
      const bf16x8 af0 = *(const bf16x8*)&h1s[(0 + ln) * HPAD + k0 + q * 8];
      const bf16x8 af1 = *(const bf16x8*)&h1s[(16 + ln) * HPAD + k0 + q * 8];
#pragma unroll
      for (int j = 0; j < 4; ++j)
        if (j < nj) {
          const bf16x8 bf = *(const bf16x8*)&Bs[(cur * 13 + w + 4 * j) * 512 + ln * 32 + cq];
          acc[j][0] = __builtin_amdgcn_mfma_f32_16x16x32_bf16(bf, af0, acc[j][0], 0, 0, 0);
          acc[j][1] = __builtin_amdgcn_mfma_f32_16x16x32_bf16(bf, af1, acc[j][1], 0, 0, 0);
        }
    }
    __syncthreads();   // last iter read buf0; protect before next pass stages
    // epilogue: scatter float4 rows via rowidx
#pragma unroll
    for (int j = 0; j < 4; ++j)
      if (j < nj) {
        const int n4 = (tstart + w + 4 * j) * 16 + 4 * q;   // mult of 4, never splits 256
        const float4 bv = *(const float4*)&b2[e * K2_N + n4];
#pragma unroll
        for (int i = 0; i < 2; ++i) {
          const int s = rowidx[16 * i + ln];
          if (s >= 0) {
            float4 v;
            v.x = acc[j][i][0] + bv.x;
            v.y = acc[j][i][1] + bv.y;
            v.z = acc[j][i][2] + bv.z;
            v.w = acc[j][i][3] + bv.w;
            if (n4 < L_N) *(float4*)&out[(size_t)s * L_N + n4] = v;
            else          *(float4*)&out[(size_t)(B_N + s) * L_N + (n4 - L_N)] = v;
          }
        }
      }
  }
}

extern "C" void kernel_launch(void* const* d_in, const int* in_sizes, int n_in,
                              void* d_out, int out_size, void* d_ws, size_t ws_size,
                              hipStream_t stream) {
  const float* x   = (const float*)d_in[0];
  const int*   idx = (const int*)d_in[1];
  const float* W1  = (const float*)d_in[2];
  const float* b1  = (const float*)d_in[3];
  const float* W2  = (const float*)d_in[4];
  const float* b2  = (const float*)d_in[5];
  float* out = (float*)d_out;

  // ws layout (bytes), same map as before (h1 slot now unused):
  // off_al@0 (68) | cnt_al@128 (64) | order@2240 (34816 used of 36864)
  // xc@39104 ((8192+1)x1024x2) | Wt1@24,486,080 (16x416x1024x2)
  // Wt2@38,117,568 (16x512x416x2) -> 44,933,312
  char* ws = (char*)d_ws;
  int* off_al = (int*)(ws + 0);
  int* cnt_al = (int*)(ws + 128);
  int* order  = (int*)(ws + 2240);
  unsigned short* xc  = (unsigned short*)(ws + 39104);
  unsigned short* Wt1 = (unsigned short*)(ws + 24486080);
  unsigned short* Wt2 = (unsigned short*)(ws + 38117568);

  prep_kernel<<<3232, 256, 0, stream>>>(W1, W2, x, idx, Wt1, Wt2, xc,
                                        off_al, cnt_al, order);
  mlp_kernel<<<NT2, 256, 0, stream>>>(xc, Wt1, Wt2, b1, b2,
                                      off_al, cnt_al, order, out);
}